// Round 6
// baseline (127.119 us; speedup 1.0000x reference)
//
#include <hip/hip_runtime.h>

#define NB 8192
#define ND 128
#define MARGINF 0.3f
#define FLTMAX 3.402823466e+38f
#define TAIL_START 1024
#define TAIL_CHUNKS 28     // (8192-1024)/256

// d_ws layout (bytes):
//   [0]      float row_loss[8192]   (-1.0f sentinel = unresolved after main+deep)
//   [32768]  float dap_g[8192]      (dist_ap, sentinel rows only)
//   [65536]  float dval[8192]       (an[r][r], sentinel rows only)
//   [98304]  u64   idxval[8192]     (packed (col<<32)|bits(an), ~0 = no hit yet)

__device__ __forceinline__ float dot4(float4 x, float4 y) {
    return x.x * y.x + x.y * y.y + x.z * y.z + x.w * y.w;
}

// Butterfly sum within each 32-lane half.
__device__ __forceinline__ float half_reduce(float v) {
    v += __shfl_xor(v, 1, 64);
    v += __shfl_xor(v, 2, 64);
    v += __shfl_xor(v, 4, 64);
    v += __shfl_xor(v, 8, 64);
    v += __shfl_xor(v, 16, 64);
    return v;
}

// Lane owning local column c (c in [0,64)): col(L) = 2*(L&31) + (L>>5).
__device__ __forceinline__ int owner(int c) {
    return (c & 1) ? 32 + (c >> 1) : (c >> 1);
}

__device__ __forceinline__ int first_col_from_mask(unsigned long long mask) {
    const unsigned int lo = (unsigned int)mask;          // even local cols
    const unsigned int hi = (unsigned int)(mask >> 32);  // odd local cols
    const int ce = lo ? 2 * (__ffs(lo) - 1)     : 0x7fffffff;
    const int co = hi ? 2 * (__ffs(hi) - 1) + 1 : 0x7fffffff;
    return ce < co ? ce : co;
}

__global__ __launch_bounds__(256) void triplet_main(const float* __restrict__ a,
                                                    const float* __restrict__ p,
                                                    const float* __restrict__ n,
                                                    float* __restrict__ row_loss,
                                                    float* __restrict__ dap_g,
                                                    float* __restrict__ dval,
                                                    unsigned long long* __restrict__ idxval) {
    __shared__ float s_dap[4];
    __shared__ int   s_state[4];
    __shared__ int   s_fc[4];
    __shared__ float s_fv[4];
    const int tid  = threadIdx.x;
    const int wave = tid >> 6;
    const int lane = tid & 63;
    const int q    = lane & 31;
    const int h    = lane >> 5;
    const int row  = blockIdx.x * 4 + wave;

    const float4 a4 = *(const float4*)(a + (size_t)row * ND + q * 4);
    const float4 p4 = *(const float4*)(p + (size_t)row * ND + q * 4);
    const float dist_ap = half_reduce(dot4(a4, p4));
    const float thresh  = dist_ap + MARGINF;

    // Phase 1: 4 mini-tiles of 16 columns, early exit (expected exit: tile 0).
    bool resolved = false;
    float diag_v = 0.f;
    for (int t = 0; t < 4 && !resolved; ++t) {
        float myval = FLTMAX;
        #pragma unroll
        for (int k = 0; k < 8; ++k) {
            const int col = t * 16 + 2 * k + h;
            const float4 nv = *(const float4*)(n + (size_t)col * ND + q * 4);
            const float v = half_reduce(dot4(a4, nv));
            if (q == k) myval = v;
        }
        if ((row >> 4) == t)   // only possible for row < 64
            diag_v = __shfl(myval, owner(row & 15), 64);
        const unsigned long long mask = __ballot(myval < thresh);
        if (mask) {  // wave-uniform
            const int c = first_col_from_mask(mask);
            const float dist_an = __shfl(myval, owner(c), 64);
            if (lane == 0) {
                const float l = dist_an - dist_ap + MARGINF;
                row_loss[row] = l > 0.f ? l : 0.f;
            }
            resolved = true;
        }
    }
    if (lane == 0) {
        s_state[wave] = resolved ? 0 : 1;
        s_dap[wave]   = dist_ap;
        if (!resolved && row < 64) dval[row] = diag_v;
    }
    __syncthreads();

    // Deep phase: block-cooperative, in-order 256-col rounds over [64, 1024).
    for (int w = 0; w < 4; ++w) {
        if (!s_state[w]) continue;
        const int r = blockIdx.x * 4 + w;
        const float th = s_dap[w] + MARGINF;
        const float4 ar = *(const float4*)(a + (size_t)r * ND + q * 4);
        bool found = false;
        for (int base = 64; base < TAIL_START; base += 256) {
            const int tb = base + wave * 64;
            float myval = FLTMAX;
            if (tb < TAIL_START) {
                #pragma unroll
                for (int k = 0; k < 32; ++k) {
                    const int col = tb + 2 * k + h;
                    const float4 nv = *(const float4*)(n + (size_t)col * ND + q * 4);
                    const float v = half_reduce(dot4(ar, nv));
                    if (q == k) myval = v;
                }
                if (r >= tb && r < tb + 64) {   // diag in this tile
                    const float dv = __shfl(myval, owner(r - tb), 64);
                    if (lane == 0) dval[r] = dv;
                }
            }
            const unsigned long long mask = __ballot(myval < th);
            int fc = 0x7fffffff; float fv = 0.f;
            if (mask) {
                const int c = first_col_from_mask(mask);
                fc = tb + c;
                fv = __shfl(myval, owner(c), 64);
            }
            if (lane == 0) { s_fc[wave] = fc; s_fv[wave] = fv; }
            __syncthreads();
            int best = 0x7fffffff; float bv = 0.f;
            #pragma unroll
            for (int j = 0; j < 4; ++j)
                if (s_fc[j] < best) { best = s_fc[j]; bv = s_fv[j]; }
            __syncthreads();   // s_fc reusable next round
            if (best != 0x7fffffff) {
                if (tid == 0) {
                    const float l = bv - s_dap[w] + MARGINF;
                    row_loss[r] = l > 0.f ? l : 0.f;
                }
                found = true;
                break;
            }
        }
        if (!found && tid == 0) {
            row_loss[r] = -1.0f;            // sentinel: tail kernel takes over
            dap_g[r]    = s_dap[w];
            idxval[r]   = ~0ULL;
        }
    }
}

// Tail: pairs (row, 256-col chunk) over cols [1024, 8192); resolved rows skip in 1 load.
__global__ __launch_bounds__(256) void triplet_tail(const float* __restrict__ a,
                                                    const float* __restrict__ n,
                                                    const float* __restrict__ row_loss,
                                                    const float* __restrict__ dap_g,
                                                    float* __restrict__ dval,
                                                    unsigned long long* __restrict__ idxval) {
    const int tid  = threadIdx.x;
    const int wave = tid >> 6;
    const int lane = tid & 63;
    const int q    = lane & 31;
    const int h    = lane >> 5;
    const int npairs = NB * TAIL_CHUNKS;

    for (int pair = blockIdx.x; pair < npairs; pair += gridDim.x) {
        const int row   = pair & (NB - 1);
        const int chunk = pair >> 13;
        if (row_loss[row] >= 0.f) continue;          // resolved: 1 broadcast load
        const float th = dap_g[row] + MARGINF;
        const float4 ar = *(const float4*)(a + (size_t)row * ND + q * 4);
        const int tb = TAIL_START + chunk * 256 + wave * 64;

        float myval = FLTMAX;
        #pragma unroll
        for (int k = 0; k < 32; ++k) {
            const int col = tb + 2 * k + h;
            const float4 nv = *(const float4*)(n + (size_t)col * ND + q * 4);
            const float v = half_reduce(dot4(ar, nv));
            if (q == k) myval = v;
        }
        if (row >= tb && row < tb + 64) {            // diag (single writer pair)
            const float dv = __shfl(myval, owner(row - tb), 64);
            if (lane == 0) dval[row] = dv;
        }
        const unsigned long long mask = __ballot(myval < th);
        if (mask) {
            const int c = first_col_from_mask(mask);
            const float fv = __shfl(myval, owner(c), 64);
            if (lane == 0) {
                const unsigned long long key =
                    ((unsigned long long)(tb + c) << 32) | (unsigned long long)__float_as_uint(fv);
                atomicMin(&idxval[row], key);        // min col wins; order-independent
            }
        }
    }
}

__global__ __launch_bounds__(256) void reduce_final(const float* __restrict__ row_loss,
                                                    const float* __restrict__ dap_g,
                                                    const float* __restrict__ dval,
                                                    const unsigned long long* __restrict__ idxval,
                                                    float* __restrict__ out) {
    __shared__ float s[256];
    float sum = 0.f;
    for (int i = threadIdx.x; i < NB; i += 256) {    // fixed order, deterministic
        float v = row_loss[i];
        if (v < 0.f) {                               // sentinel: finish here
            const unsigned long long u = idxval[i];
            const float an_v = (u != ~0ULL) ? __uint_as_float((unsigned int)u) : dval[i];
            const float l = an_v - dap_g[i] + MARGINF;
            v = l > 0.f ? l : 0.f;
        }
        sum += v;
    }
    s[threadIdx.x] = sum;
    __syncthreads();
    #pragma unroll
    for (int off = 128; off; off >>= 1) {
        if ((int)threadIdx.x < off) s[threadIdx.x] += s[threadIdx.x + off];
        __syncthreads();
    }
    if (threadIdx.x == 0) out[0] = s[0] / (float)NB;
}

extern "C" void kernel_launch(void* const* d_in, const int* in_sizes, int n_in,
                              void* d_out, int out_size, void* d_ws, size_t ws_size,
                              hipStream_t stream) {
    const float* a = (const float*)d_in[0];
    const float* p = (const float*)d_in[1];
    const float* n = (const float*)d_in[2];
    char* ws = (char*)d_ws;
    float*              row_loss = (float*)ws;
    float*              dap_g    = (float*)(ws + 32768);
    float*              dval     = (float*)(ws + 65536);
    unsigned long long* idxval   = (unsigned long long*)(ws + 98304);
    float* out = (float*)d_out;

    triplet_main<<<NB / 4, 256, 0, stream>>>(a, p, n, row_loss, dap_g, dval, idxval);
    triplet_tail<<<2048, 256, 0, stream>>>(a, n, row_loss, dap_g, dval, idxval);
    reduce_final<<<1, 256, 0, stream>>>(row_loss, dap_g, dval, idxval, out);
}